// Round 2
// baseline (1444.092 us; speedup 1.0000x reference)
//
#include <hip/hip_runtime.h>
#include <hip/hip_bf16.h>

#define B_ 16
#define S_ 2048
#define D_ 512
#define M_ (B_ * S_)  // 32768 rows for the GEMMs

typedef __attribute__((ext_vector_type(8))) _Float16 f16x8;
typedef __attribute__((ext_vector_type(4))) float f32x4;

// ---------------------------------------------------------------------------
// Weight prep: cast fp32 W[l][h][512][1024] -> fp16 Wt[mat][1024][512]
// (transposed so B-operand fragments are contiguous 16B runs in k).
// mat index = (l*2 + dir)*2 + h
// fp16 (not bf16): threshold is ~1 bf16 ulp of absmax; bf16 GEMM rounding
// amplified via sigmoid-gate * large-x gave absmax err 4.5 (R1). fp16 cuts
// input rounding 8x.
// ---------------------------------------------------------------------------
__global__ __launch_bounds__(256) void prep_w_kernel(
    const float* __restrict__ fwW, const float* __restrict__ bwW,
    _Float16* __restrict__ Wt)
{
    long long gid = (long long)blockIdx.x * 256 + threadIdx.x;  // 8*512*1024
    int mat = (int)(gid >> 19);
    int rem = (int)(gid & ((1 << 19) - 1));
    int n = rem >> 9;       // 0..1023 (proj column)
    int k = rem & 511;      // 0..511
    int l   = mat >> 2;
    int dir = (mat >> 1) & 1;
    int h   = mat & 1;
    const float* src = (dir ? bwW : fwW) + (long long)(l * 2 + h) * (512LL * 1024);
    Wt[gid] = (_Float16)(src[k * 1024 + n]);
}

// ---------------------------------------------------------------------------
// Band conv along S. causal: y[t] = sum_e w[e]*x[t-16+e]; anticausal:
// y[t] = sum_e w[e]*x[t+e]. Unified: buf[i] = x[t0 + i - (causal?16:0)].
// 4 outputs per thread (20 loads -> 4 outputs). Writes fp32 (optional) + fp16.
// ---------------------------------------------------------------------------
__global__ __launch_bounds__(256) void band_conv_kernel(
    const float* __restrict__ src, long long bstride, int rstride,
    const float* __restrict__ w17, int causal,
    float* __restrict__ Tf, _Float16* __restrict__ Th)
{
    int id = blockIdx.x * 256 + threadIdx.x;  // B * (S/4) * D threads
    int c  = id & (D_ - 1);
    int tt = (id >> 9) & (S_ / 4 - 1);
    int b  = id >> 18;
    int t0 = tt * 4;

    float w[17];
#pragma unroll
    for (int e = 0; e < 17; ++e) w[e] = w17[e];

    float buf[20];
    int tbase = t0 - (causal ? 16 : 0);
    const float* sp = src + (long long)b * bstride + c;
#pragma unroll
    for (int i = 0; i < 20; ++i) {
        int t = tbase + i;
        buf[i] = (t >= 0 && t < S_) ? sp[(long long)t * rstride] : 0.f;
    }
#pragma unroll
    for (int j = 0; j < 4; ++j) {
        float a = 0.f;
#pragma unroll
        for (int e = 0; e <= 16; ++e) a = fmaf(w[e], buf[j + e], a);
        long long o = ((long long)(b * S_ + t0 + j)) * D_ + c;
        if (Tf) Tf[o] = a;
        Th[o] = (_Float16)a;
    }
}

// ---------------------------------------------------------------------------
// One highway iteration, fused: proj = X(fp16) @ W(fp16) + b, then
// out = sigmoid(gate)*x + (1-sigmoid(gate))*relu(nonlinear).
// Block: 128 M-rows x 64 output cols; computes BOTH proj halves (cols n0..+64
// and 512+n0..+64) so the epilogue fuses in-register.
// 4 waves: wave&1 -> M half (64 rows), wave>>1 -> 32-col half.
// MFMA 16x16x32 f16; verified layouts (dtype-independent on gfx950):
//   A frag: A[m=lane&15][k=quad*8+j]; B frag: B[k=quad*8+j][n=lane&15]
//   C/D:    row(m)=quad*4+reg, col(n)=lane&15
// ---------------------------------------------------------------------------
__global__ __launch_bounds__(256) void hw_step_kernel(
    const _Float16* __restrict__ Xh,         // [M][512] fp16 GEMM input
    const float* __restrict__ Xf,            // [M][512] fp32 x (may be null)
    const _Float16* __restrict__ Wt,         // [1024][512] fp16 (k-contig)
    const float* __restrict__ bias,          // [1024]
    float* __restrict__ outF, int outF_stride,  // may be null
    _Float16* __restrict__ outH)                // may be null
{
    __shared__ _Float16 As[128 * 32];
    __shared__ _Float16 Bs[128 * 32];  // rows 0..63: nonlinear cols, 64..127: gate

    int tid  = threadIdx.x;
    long long m0 = (long long)blockIdx.x * 128;
    int n0   = blockIdx.y * 64;       // output-column base (0..511 space)
    int lane = tid & 63;
    int wave = tid >> 6;
    int wm   = (wave & 1) * 64;
    int wn   = (wave >> 1) * 32;
    int ln   = lane & 15;
    int q    = lane >> 4;

    f32x4 acc[2][2][4];
#pragma unroll
    for (int h = 0; h < 2; ++h)
#pragma unroll
        for (int jn = 0; jn < 2; ++jn)
#pragma unroll
            for (int i = 0; i < 4; ++i) acc[h][jn][i] = (f32x4){0.f, 0.f, 0.f, 0.f};

    int srow = tid >> 2;        // 0..63
    int scol = (tid & 3) * 8;   // fp16 offset in 32-wide k row

    for (int k0 = 0; k0 < 512; k0 += 32) {
        __syncthreads();
        *(f16x8*)&As[srow * 32 + scol] =
            *(const f16x8*)&Xh[(m0 + srow) * 512 + k0 + scol];
        *(f16x8*)&As[(srow + 64) * 32 + scol] =
            *(const f16x8*)&Xh[(m0 + srow + 64) * 512 + k0 + scol];
        *(f16x8*)&Bs[srow * 32 + scol] =
            *(const f16x8*)&Wt[(long long)(n0 + srow) * 512 + k0 + scol];
        *(f16x8*)&Bs[(srow + 64) * 32 + scol] =
            *(const f16x8*)&Wt[(long long)(512 + n0 + srow) * 512 + k0 + scol];
        __syncthreads();

        f16x8 af[4];
#pragma unroll
        for (int i = 0; i < 4; ++i)
            af[i] = *(const f16x8*)&As[(wm + i * 16 + ln) * 32 + q * 8];
        f16x8 bfr[2][2];
#pragma unroll
        for (int h = 0; h < 2; ++h)
#pragma unroll
            for (int jn = 0; jn < 2; ++jn)
                bfr[h][jn] = *(const f16x8*)&Bs[(h * 64 + wn + jn * 16 + ln) * 32 + q * 8];
#pragma unroll
        for (int h = 0; h < 2; ++h)
#pragma unroll
            for (int jn = 0; jn < 2; ++jn)
#pragma unroll
                for (int i = 0; i < 4; ++i)
                    acc[h][jn][i] = __builtin_amdgcn_mfma_f32_16x16x32_f16(
                        af[i], bfr[h][jn], acc[h][jn][i], 0, 0, 0);
    }

    // Fused highway epilogue
#pragma unroll
    for (int jn = 0; jn < 2; ++jn) {
        int c = n0 + wn + jn * 16 + ln;   // 0..511
        float bnl = bias[c];
        float bg  = bias[512 + c];
#pragma unroll
        for (int i = 0; i < 4; ++i) {
#pragma unroll
            for (int r = 0; r < 4; ++r) {
                long long m = m0 + wm + i * 16 + q * 4 + r;
                float nl = acc[0][jn][i][r] + bnl;
                float gt = acc[1][jn][i][r] + bg;
                float g  = 1.f / (1.f + __expf(-gt));
                float xv = Xf ? Xf[m * 512 + c]
                              : (float)Xh[m * 512 + c];
                float o  = g * xv + (1.f - g) * fmaxf(nl, 0.f);
                if (outF) outF[m * (long long)outF_stride + c] = o;
                if (outH) outH[m * 512 + c] = (_Float16)o;
            }
        }
    }
}

// ---------------------------------------------------------------------------
extern "C" void kernel_launch(void* const* d_in, const int* in_sizes, int n_in,
                              void* d_out, int out_size, void* d_ws, size_t ws_size,
                              hipStream_t stream)
{
    const float* inputs  = (const float*)d_in[0];
    // d_in[1] = masks: all ones, unused by the reference
    const float* fw_band = (const float*)d_in[2];
    const float* bw_band = (const float*)d_in[3];
    const float* fw_W    = (const float*)d_in[4];
    const float* fw_b    = (const float*)d_in[5];
    const float* bw_W    = (const float*)d_in[6];
    const float* bw_b    = (const float*)d_in[7];
    float* out = (float*)d_out;  // [2][16][2048][1024]

    char* ws = (char*)d_ws;
    const size_t SZ_TH = (size_t)M_ * D_ * 2;    // 32 MB fp16 activation
    const size_t SZ_WT = 8ULL * 1024 * 512 * 2;  // 8 MB fp16 weights
    const size_t SZ_TF = (size_t)M_ * D_ * 4;    // 64 MB fp32 activation
    _Float16* Th = (_Float16*)(ws);
    _Float16* Hh = (_Float16*)(ws + SZ_TH);
    _Float16* Wt = (_Float16*)(ws + 2 * SZ_TH);
    size_t off = 2 * SZ_TH + SZ_WT;
    // Keep fp32 x-copies if workspace allows (precision headroom); else fp16 x.
    bool f32x = (ws_size >= off + 2 * SZ_TF);
    float* Tf = f32x ? (float*)(ws + off) : nullptr;
    float* Hf = f32x ? (float*)(ws + off + SZ_TF) : nullptr;

    prep_w_kernel<<<(8 * 512 * 1024) / 256, 256, 0, stream>>>(fw_W, bw_W, Wt);

    dim3 ggrid(M_ / 128, 8);
    for (int l = 0; l < 2; ++l) {
        for (int dir = 0; dir < 2; ++dir) {
            const float* src; long long bstride; int rstride;
            if (l == 0) { src = inputs; bstride = (long long)S_ * D_; rstride = D_; }
            else {
                src = out + (long long)(l - 1) * M_ * 1024 + dir * 512;
                bstride = (long long)S_ * 1024; rstride = 1024;
            }
            const float* band = (dir ? bw_band : fw_band) + l * 17;
            band_conv_kernel<<<(B_ * (S_ / 4) * D_) / 256, 256, 0, stream>>>(
                src, bstride, rstride, band, dir == 0 ? 1 : 0, Tf, Th);

            const _Float16* W0 = Wt + (size_t)((l * 2 + dir) * 2 + 0) * (1024 * 512);
            const _Float16* W1 = Wt + (size_t)((l * 2 + dir) * 2 + 1) * (1024 * 512);
            const float* bias = (dir ? bw_b : fw_b) + (size_t)(l * 2) * 1024;

            // highway iter 0: Th -> Hh (+Hf)
            hw_step_kernel<<<ggrid, 256, 0, stream>>>(Th, Tf, W0, bias, Hf, 512, Hh);
            // highway iter 1: Hh -> d_out slice (fp32, stride 1024)
            float* oF = out + (long long)l * M_ * 1024 + dir * 512;
            hw_step_kernel<<<ggrid, 256, 0, stream>>>(Hh, Hf, W1, bias + 1024, oF, 1024, nullptr);
        }
    }
}

// Round 3
// 1085.771 us; speedup vs baseline: 1.3300x; 1.3300x over previous
//
#include <hip/hip_runtime.h>
#include <hip/hip_bf16.h>

#define B_ 16
#define S_ 2048
#define D_ 512
#define M_ (B_ * S_)  // 32768 rows for the GEMMs

typedef __attribute__((ext_vector_type(8))) _Float16 f16x8;
typedef __attribute__((ext_vector_type(4))) float f32x4;

// Async global->LDS direct copy, 16B per lane. LDS dest must be
// wave-uniform base + lane*16 (our staging layout satisfies this: tid*16B).
#define GLOAD_LDS16(gp, lp)                                                   \
    __builtin_amdgcn_global_load_lds(                                         \
        (const __attribute__((address_space(1))) unsigned int*)(gp),          \
        (__attribute__((address_space(3))) unsigned int*)(lp), 16, 0, 0)

// ---------------------------------------------------------------------------
// Weight prep: cast fp32 W[l][h][512][1024] -> fp16 Wt[mat][1024][512]
// (transposed so B-operand fragments are contiguous 16B runs in k).
// mat index = (l*2 + dir)*2 + h
// fp16 (not bf16): bf16 GEMM rounding amplified via sigmoid-gate * large-x
// gave absmax 4.5 > 1.68 (R1); fp16 cuts input rounding 8x -> 0.64 (R2).
// ---------------------------------------------------------------------------
__global__ __launch_bounds__(256) void prep_w_kernel(
    const float* __restrict__ fwW, const float* __restrict__ bwW,
    _Float16* __restrict__ Wt)
{
    long long gid = (long long)blockIdx.x * 256 + threadIdx.x;  // 8*512*1024
    int mat = (int)(gid >> 19);
    int rem = (int)(gid & ((1 << 19) - 1));
    int n = rem >> 9;       // 0..1023 (proj column)
    int k = rem & 511;      // 0..511
    int l   = mat >> 2;
    int dir = (mat >> 1) & 1;
    int h   = mat & 1;
    const float* src = (dir ? bwW : fwW) + (long long)(l * 2 + h) * (512LL * 1024);
    Wt[gid] = (_Float16)(src[k * 1024 + n]);
}

// ---------------------------------------------------------------------------
// Band conv along S. causal: y[t] = sum_e w[e]*x[t-16+e]; anticausal:
// y[t] = sum_e w[e]*x[t+e]. Unified: buf[i] = x[t0 + i - (causal?16:0)].
// 4 outputs per thread (20 loads -> 4 outputs). fp16 output only (R2: fp32
// side-buffers dropped; epilogue x reads the fp16 copy, costs <=0.125 absmax
// per highway step, saves ~1 GB HBM).
// ---------------------------------------------------------------------------
__global__ __launch_bounds__(256) void band_conv_kernel(
    const float* __restrict__ src, long long bstride, int rstride,
    const float* __restrict__ w17, int causal,
    _Float16* __restrict__ Th)
{
    int id = blockIdx.x * 256 + threadIdx.x;  // B * (S/4) * D threads
    int c  = id & (D_ - 1);
    int tt = (id >> 9) & (S_ / 4 - 1);
    int b  = id >> 18;
    int t0 = tt * 4;

    float w[17];
#pragma unroll
    for (int e = 0; e < 17; ++e) w[e] = w17[e];

    float buf[20];
    int tbase = t0 - (causal ? 16 : 0);
    const float* sp = src + (long long)b * bstride + c;
#pragma unroll
    for (int i = 0; i < 20; ++i) {
        int t = tbase + i;
        buf[i] = (t >= 0 && t < S_) ? sp[(long long)t * rstride] : 0.f;
    }
#pragma unroll
    for (int j = 0; j < 4; ++j) {
        float a = 0.f;
#pragma unroll
        for (int e = 0; e <= 16; ++e) a = fmaf(w[e], buf[j + e], a);
        Th[((long long)(b * S_ + t0 + j)) * D_ + c] = (_Float16)a;
    }
}

// ---------------------------------------------------------------------------
// One highway iteration, fused: proj = X(fp16) @ W(fp16) + b, then
// out = sigmoid(gate)*x + (1-sigmoid(gate))*relu(nonlinear).
// Block: 128 M-rows x 64 output cols; computes BOTH proj halves (cols n0..+64
// and 512+n0..+64) so the epilogue fuses in-register.
// 4 waves: wave&1 -> M half (64 rows), wave>>1 -> 32-col half.
// Staging via global_load_lds width=16 (m97 pattern): LDS addr = tid*16B =
// wave-uniform base + lane*16B within each wave, as required.
// MFMA 16x16x32 f16; verified layouts (dtype-independent on gfx950):
//   A frag: A[m=lane&15][k=quad*8+j]; B frag: B[k=quad*8+j][n=lane&15]
//   C/D:    row(m)=quad*4+reg, col(n)=lane&15
// ---------------------------------------------------------------------------
__global__ __launch_bounds__(256) void hw_step_kernel(
    const _Float16* __restrict__ Xh,         // [M][512] fp16 GEMM + x input
    const _Float16* __restrict__ Wt,         // [1024][512] fp16 (k-contig)
    const float* __restrict__ bias,          // [1024]
    float* __restrict__ outF, int outF_stride,  // may be null
    _Float16* __restrict__ outH)                // may be null
{
    __shared__ _Float16 As[128 * 32];
    __shared__ _Float16 Bs[128 * 32];  // rows 0..63: nonlinear cols, 64..127: gate

    int tid  = threadIdx.x;
    long long m0 = (long long)blockIdx.x * 128;
    int n0   = blockIdx.y * 64;       // output-column base (0..511 space)
    int lane = tid & 63;
    int wave = tid >> 6;
    int wm   = (wave & 1) * 64;
    int wn   = (wave >> 1) * 32;
    int ln   = lane & 15;
    int q    = lane >> 4;

    f32x4 acc[2][2][4];
#pragma unroll
    for (int h = 0; h < 2; ++h)
#pragma unroll
        for (int jn = 0; jn < 2; ++jn)
#pragma unroll
            for (int i = 0; i < 4; ++i) acc[h][jn][i] = (f32x4){0.f, 0.f, 0.f, 0.f};

    int srow = tid >> 2;        // 0..63
    int scol = (tid & 3) * 8;   // fp16 offset in 32-wide k row
    const _Float16* gA0 = Xh + (m0 + srow) * 512 + scol;
    const _Float16* gA1 = gA0 + 64 * 512;
    const _Float16* gB0 = Wt + (long long)(n0 + srow) * 512 + scol;
    const _Float16* gB1 = gB0 + 512 * 512;
    _Float16* lA = &As[tid * 8];   // == base + lane*16B within each wave
    _Float16* lB = &Bs[tid * 8];

    for (int k0 = 0; k0 < 512; k0 += 32) {
        __syncthreads();   // previous tile fully consumed
        GLOAD_LDS16(gA0 + k0, lA);
        GLOAD_LDS16(gA1 + k0, lA + 64 * 32);
        GLOAD_LDS16(gB0 + k0, lB);
        GLOAD_LDS16(gB1 + k0, lB + 64 * 32);
        __syncthreads();   // compiler emits s_waitcnt vmcnt(0) before barrier

        f16x8 af[4];
#pragma unroll
        for (int i = 0; i < 4; ++i)
            af[i] = *(const f16x8*)&As[(wm + i * 16 + ln) * 32 + q * 8];
        f16x8 bfr[2][2];
#pragma unroll
        for (int h = 0; h < 2; ++h)
#pragma unroll
            for (int jn = 0; jn < 2; ++jn)
                bfr[h][jn] = *(const f16x8*)&Bs[(h * 64 + wn + jn * 16 + ln) * 32 + q * 8];
#pragma unroll
        for (int h = 0; h < 2; ++h)
#pragma unroll
            for (int jn = 0; jn < 2; ++jn)
#pragma unroll
                for (int i = 0; i < 4; ++i)
                    acc[h][jn][i] = __builtin_amdgcn_mfma_f32_16x16x32_f16(
                        af[i], bfr[h][jn], acc[h][jn][i], 0, 0, 0);
    }

    // Fused highway epilogue
#pragma unroll
    for (int jn = 0; jn < 2; ++jn) {
        int c = n0 + wn + jn * 16 + ln;   // 0..511
        float bnl = bias[c];
        float bg  = bias[512 + c];
#pragma unroll
        for (int i = 0; i < 4; ++i) {
#pragma unroll
            for (int r = 0; r < 4; ++r) {
                long long m = m0 + wm + i * 16 + q * 4 + r;
                float nl = acc[0][jn][i][r] + bnl;
                float gt = acc[1][jn][i][r] + bg;
                float g  = 1.f / (1.f + __expf(-gt));
                float xv = (float)Xh[m * 512 + c];
                float o  = g * xv + (1.f - g) * fmaxf(nl, 0.f);
                if (outF) outF[m * (long long)outF_stride + c] = o;
                if (outH) outH[m * 512 + c] = (_Float16)o;
            }
        }
    }
}

// ---------------------------------------------------------------------------
extern "C" void kernel_launch(void* const* d_in, const int* in_sizes, int n_in,
                              void* d_out, int out_size, void* d_ws, size_t ws_size,
                              hipStream_t stream)
{
    const float* inputs  = (const float*)d_in[0];
    // d_in[1] = masks: all ones, unused by the reference
    const float* fw_band = (const float*)d_in[2];
    const float* bw_band = (const float*)d_in[3];
    const float* fw_W    = (const float*)d_in[4];
    const float* fw_b    = (const float*)d_in[5];
    const float* bw_W    = (const float*)d_in[6];
    const float* bw_b    = (const float*)d_in[7];
    float* out = (float*)d_out;  // [2][16][2048][1024]

    char* ws = (char*)d_ws;
    const size_t SZ_TH = (size_t)M_ * D_ * 2;    // 32 MB fp16 activation
    _Float16* Th = (_Float16*)(ws);
    _Float16* Hh = (_Float16*)(ws + SZ_TH);
    _Float16* Wt = (_Float16*)(ws + 2 * SZ_TH);  // 8 MB fp16 weights

    prep_w_kernel<<<(8 * 512 * 1024) / 256, 256, 0, stream>>>(fw_W, bw_W, Wt);

    dim3 ggrid(M_ / 128, 8);
    for (int l = 0; l < 2; ++l) {
        for (int dir = 0; dir < 2; ++dir) {
            const float* src; long long bstride; int rstride;
            if (l == 0) { src = inputs; bstride = (long long)S_ * D_; rstride = D_; }
            else {
                src = out + (long long)(l - 1) * M_ * 1024 + dir * 512;
                bstride = (long long)S_ * 1024; rstride = 1024;
            }
            const float* band = (dir ? bw_band : fw_band) + l * 17;
            band_conv_kernel<<<(B_ * (S_ / 4) * D_) / 256, 256, 0, stream>>>(
                src, bstride, rstride, band, dir == 0 ? 1 : 0, Th);

            const _Float16* W0 = Wt + (size_t)((l * 2 + dir) * 2 + 0) * (1024 * 512);
            const _Float16* W1 = Wt + (size_t)((l * 2 + dir) * 2 + 1) * (1024 * 512);
            const float* bias = (dir ? bw_b : fw_b) + (size_t)(l * 2) * 1024;

            // highway iter 0: Th -> Hh
            hw_step_kernel<<<ggrid, 256, 0, stream>>>(Th, W0, bias, nullptr, 0, Hh);
            // highway iter 1: Hh -> d_out slice (fp32, stride 1024)
            float* oF = out + (long long)l * M_ * 1024 + dir * 512;
            hw_step_kernel<<<ggrid, 256, 0, stream>>>(Hh, W1, bias + 1024, oF, 1024, nullptr);
        }
    }
}